// Round 1
// baseline (2717.425 us; speedup 1.0000x reference)
//
#include <hip/hip_runtime.h>

// Net_39135742001869: S2VT video-caption LSTM (enc 80 + dec 39 steps), bf16 MFMA.

typedef unsigned short u16;
typedef __attribute__((ext_vector_type(8))) short s8v;   // 8 x bf16 (as short)
typedef __attribute__((ext_vector_type(4))) float f4v;   // MFMA accumulator

#define VOC   6000
#define VOCP  6016        // padded to multiple of 128
#define CHUNK_M 3328      // 3 x 3328 = 9984 decode rows

__device__ __forceinline__ u16 f2b(float f) {
  unsigned u = __float_as_uint(f);
  unsigned r = (u + 0x7fffu + ((u >> 16) & 1u)) >> 16;   // RNE f32->bf16
  return (u16)r;
}
__device__ __forceinline__ float sigm(float x) { return 1.f / (1.f + __expf(-x)); }
__device__ __forceinline__ float tanh_f(float x) {
  float e = __expf(-2.f * fabsf(x));
  float t = (1.f - e) / (1.f + e);
  return x >= 0.f ? t : -t;
}

// ---------------- weight pack (f32 -> bf16, optional strided slice + zero pad rows) ----
__global__ void pack_bf16(u16* __restrict__ dst, int dld, int doff,
                          const float* __restrict__ src, int sld, int soff,
                          int Wc, int R, int Rsrc) {
  int i = blockIdx.x * 256 + threadIdx.x;
  if (i >= Wc * R) return;
  int r = i / Wc, c = i - r * Wc;
  float v = (r < Rsrc) ? src[(size_t)r * sld + soff + c] : 0.f;
  dst[(size_t)r * dld + doff + c] = f2b(v);
}

__global__ void bias_setup(const float* __restrict__ bi1, const float* __restrict__ bh1,
                           const float* __restrict__ bi2, const float* __restrict__ bh2,
                           const float* __restrict__ bo,
                           float* __restrict__ b1s, float* __restrict__ b2s,
                           float* __restrict__ bop) {
  int i = blockIdx.x * 256 + threadIdx.x;
  if (i < 1024) { b1s[i] = bi1[i] + bh1[i]; b2s[i] = bi2[i] + bh2[i]; }
  if (i < VOCP) bop[i] = (i < VOC) ? bo[i] : 0.f;
}

// ---------------- targets = argmax(caption_one_hot[b, d+1, :]) --------------------------
__global__ __launch_bounds__(256) void argmax_kernel(const float* __restrict__ coh,
                                                     int* __restrict__ tgt) {
  const int d = blockIdx.x >> 8;       // 0..38
  const int b = blockIdx.x & 255;
  const float* row = coh + ((size_t)b * 40 + (d + 1)) * VOC;
  float best = -3.4e38f; int bi = 0;
  for (int n = threadIdx.x; n < VOC; n += 256) {
    float v = row[n];
    if (v > best) { best = v; bi = n; }
  }
#pragma unroll
  for (int o = 1; o < 64; o <<= 1) {
    float ov = __shfl_xor(best, o);
    int   oi = __shfl_xor(bi, o);
    if (ov > best || (ov == best && oi < bi)) { best = ov; bi = oi; }
  }
  __shared__ float sv[4]; __shared__ int si[4];
  if ((threadIdx.x & 63) == 0) { sv[threadIdx.x >> 6] = best; si[threadIdx.x >> 6] = bi; }
  __syncthreads();
  if (threadIdx.x == 0) {
    for (int i = 1; i < 4; ++i)
      if (sv[i] > best || (sv[i] == best && si[i] < bi)) { best = sv[i]; bi = si[i]; }
    tgt[blockIdx.x] = bi;              // layout [d][b]
  }
}

// ---------------- generic GEMM: C[M][ldc] = A_f32[M][K] * Bw_bf16[N][K]^T + bias --------
// grid = (N/128, M/128); M,N multiples of 128, K multiple of 64.
__global__ __launch_bounds__(256) void gemm_bf16(
    const float* __restrict__ A, const u16* __restrict__ Bw,
    const float* __restrict__ bias, float* __restrict__ C,
    int K, int lda, int ldc)
{
  const int n0 = blockIdx.x * 128;
  const int m0 = blockIdx.y * 128;
  const int tid = threadIdx.x;
  const int lane = tid & 63;
  const int wid = tid >> 6;
  const int wm = wid >> 1, wn = wid & 1;
  const int fr = lane & 15;
  const int fk = (lane >> 4) * 8;
  const int sr = tid >> 1;
  const int sc = (tid & 1) * 32;

  __shared__ u16 As[128][72];   // row stride 144B = 9x16B (pad kills bank conflicts)
  __shared__ u16 Bs[128][72];
  f4v acc[4][4] = {};

  for (int k0 = 0; k0 < K; k0 += 64) {
    const float* ap = A + (size_t)(m0 + sr) * lda + (k0 + sc);
    const u16*   bp = Bw + (size_t)(n0 + sr) * K + (k0 + sc);
    float af[32];
#pragma unroll
    for (int v = 0; v < 8; ++v) {
      float4 t4 = *reinterpret_cast<const float4*>(ap + v * 4);
      af[v*4+0] = t4.x; af[v*4+1] = t4.y; af[v*4+2] = t4.z; af[v*4+3] = t4.w;
    }
    int4 bv[4];
#pragma unroll
    for (int v = 0; v < 4; ++v) bv[v] = *reinterpret_cast<const int4*>(bp + v * 8);
    __syncthreads();
#pragma unroll
    for (int v = 0; v < 4; ++v) {
      int w0 = (int)((unsigned)f2b(af[v*8+0]) | ((unsigned)f2b(af[v*8+1]) << 16));
      int w1 = (int)((unsigned)f2b(af[v*8+2]) | ((unsigned)f2b(af[v*8+3]) << 16));
      int w2 = (int)((unsigned)f2b(af[v*8+4]) | ((unsigned)f2b(af[v*8+5]) << 16));
      int w3 = (int)((unsigned)f2b(af[v*8+6]) | ((unsigned)f2b(af[v*8+7]) << 16));
      *reinterpret_cast<int4*>(&As[sr][sc + v*8]) = make_int4(w0, w1, w2, w3);
      *reinterpret_cast<int4*>(&Bs[sr][sc + v*8]) = bv[v];
    }
    __syncthreads();
#pragma unroll
    for (int ks = 0; ks < 2; ++ks) {
      const int kb = ks * 32 + fk;
      s8v a[4], b[4];
#pragma unroll
      for (int i = 0; i < 4; ++i)
        a[i] = *reinterpret_cast<const s8v*>(&As[wm*64 + i*16 + fr][kb]);
#pragma unroll
      for (int j = 0; j < 4; ++j)
        b[j] = *reinterpret_cast<const s8v*>(&Bs[wn*64 + j*16 + fr][kb]);
#pragma unroll
      for (int i = 0; i < 4; ++i)
#pragma unroll
        for (int j = 0; j < 4; ++j)
          acc[i][j] = __builtin_amdgcn_mfma_f32_16x16x32_bf16(a[i], b[j], acc[i][j], 0, 0, 0);
    }
  }
#pragma unroll
  for (int j = 0; j < 4; ++j) {
    const int n = n0 + wn*64 + j*16 + fr;
    const float bz = bias[n];
#pragma unroll
    for (int i = 0; i < 4; ++i) {
      const int rb = m0 + wm*64 + i*16 + (lane >> 4) * 4;
#pragma unroll
      for (int r = 0; r < 4; ++r)
        C[(size_t)(rb + r) * ldc + n] = acc[i][j][r] + bz;
    }
  }
}

// ---------------- fused recurrence step: blocks 0..63 = LSTM1(t), 64..127 = LSTM2(t-1) --
// hcat: 2 banks of [256 batch][512] bf16 = [h1 | h2]. Step t reads bank (t+1)&1, writes t&1.
__global__ __launch_bounds__(256) void step_kernel(
    int t,
    const float* __restrict__ X1,     // [b*80+t][1024], bias folded
    const float* __restrict__ Xc,     // [b*40+d][1024], bias folded
    const float* __restrict__ b1sum, const float* __restrict__ b2sum,
    const u16* __restrict__ Whh1,     // [1024][256]
    const u16* __restrict__ Wcat2,    // [1024][512] = [W_ih2[:,256:] | W_hh2]
    u16* __restrict__ hcat, float* __restrict__ c1, float* __restrict__ c2,
    float* __restrict__ H2dec)        // [39*256][256] f32
{
  const int lane = threadIdx.x & 63;
  const int w = threadIdx.x >> 6;
  const int fr = lane & 15;
  const int fk = (lane >> 4) * 8;
  const u16* hr = hcat + (size_t)((t + 1) & 1) * (256 * 512);
  u16*       hw = hcat + (size_t)(t & 1) * (256 * 512);

  if (blockIdx.x < 64) {                       // ---- phase1: LSTM1(t), t in [0,118]
    if (t > 118) return;
    const int bm = blockIdx.x >> 4;
    const int bh = blockIdx.x & 15;
    const int rowbase = bm * 64 + w * 16;
    f4v acc[4] = {};
    const u16* arow = hr + (size_t)(rowbase + fr) * 512;   // h1 cols [0,256)
#pragma unroll
    for (int kk = 0; kk < 8; ++kk) {
      const int kb = kk * 32 + fk;
      s8v a = *reinterpret_cast<const s8v*>(arow + kb);
#pragma unroll
      for (int q = 0; q < 4; ++q) {
        s8v wv = *reinterpret_cast<const s8v*>(Whh1 + (size_t)(q*256 + bh*16 + fr) * 256 + kb);
        acc[q] = __builtin_amdgcn_mfma_f32_16x16x32_bf16(a, wv, acc[q], 0, 0, 0);
      }
    }
    const int hd = bh * 16 + fr;
    float xb0 = 0, xb1 = 0, xb2 = 0, xb3 = 0;
    if (t >= 80) { xb0 = b1sum[hd]; xb1 = b1sum[256+hd]; xb2 = b1sum[512+hd]; xb3 = b1sum[768+hd]; }
#pragma unroll
    for (int r = 0; r < 4; ++r) {
      const int bat = rowbase + (lane >> 4) * 4 + r;
      float g0 = acc[0][r], g1 = acc[1][r], g2 = acc[2][r], g3 = acc[3][r];
      if (t < 80) {
        const float* xp = X1 + ((size_t)bat * 80 + t) * 1024;
        g0 += xp[hd]; g1 += xp[256+hd]; g2 += xp[512+hd]; g3 += xp[768+hd];
      } else { g0 += xb0; g1 += xb1; g2 += xb2; g3 += xb3; }
      const int ci = bat * 256 + hd;
      float co = c1[ci];
      float ii = sigm(g0), ff = sigm(g1), gg = tanh_f(g2), oo = sigm(g3);
      float cn = ff * co + ii * gg;
      float h = oo * tanh_f(cn);
      c1[ci] = cn;
      hw[(size_t)bat * 512 + hd] = f2b(h);
    }
  } else {                                     // ---- phase2: LSTM2(s=t-1), s in [0,118]
    if (t < 1) return;
    const int s = t - 1;
    const int bb = blockIdx.x - 64;
    const int bm = bb >> 4;
    const int bh = bb & 15;
    const int rowbase = bm * 64 + w * 16;
    f4v acc[4] = {};
    const u16* arow = hr + (size_t)(rowbase + fr) * 512;   // [h1(s) | h2(s-1)]
#pragma unroll
    for (int kk = 0; kk < 16; ++kk) {
      const int kb = kk * 32 + fk;
      s8v a = *reinterpret_cast<const s8v*>(arow + kb);
#pragma unroll
      for (int q = 0; q < 4; ++q) {
        s8v wv = *reinterpret_cast<const s8v*>(Wcat2 + (size_t)(q*256 + bh*16 + fr) * 512 + kb);
        acc[q] = __builtin_amdgcn_mfma_f32_16x16x32_bf16(a, wv, acc[q], 0, 0, 0);
      }
    }
    const int hd = bh * 16 + fr;
    float xb0 = 0, xb1 = 0, xb2 = 0, xb3 = 0;
    if (s < 80) { xb0 = b2sum[hd]; xb1 = b2sum[256+hd]; xb2 = b2sum[512+hd]; xb3 = b2sum[768+hd]; }
#pragma unroll
    for (int r = 0; r < 4; ++r) {
      const int bat = rowbase + (lane >> 4) * 4 + r;
      float g0 = acc[0][r], g1 = acc[1][r], g2 = acc[2][r], g3 = acc[3][r];
      if (s >= 80) {
        const float* xp = Xc + ((size_t)bat * 40 + (s - 80)) * 1024;
        g0 += xp[hd]; g1 += xp[256+hd]; g2 += xp[512+hd]; g3 += xp[768+hd];
      } else { g0 += xb0; g1 += xb1; g2 += xb2; g3 += xb3; }
      const int ci = bat * 256 + hd;
      float co = c2[ci];
      float ii = sigm(g0), ff = sigm(g1), gg = tanh_f(g2), oo = sigm(g3);
      float cn = ff * co + ii * gg;
      float h = oo * tanh_f(cn);
      c2[ci] = cn;
      hw[(size_t)bat * 512 + 256 + hd] = f2b(h);
      if (s >= 80) H2dec[((size_t)(s - 80) * 256 + bat) * 256 + hd] = h;
    }
  }
}

// ---------------- per-row logsumexp NLL over the padded logits -------------------------
__global__ __launch_bounds__(256) void nll_kernel(const float* __restrict__ logits,
                                                  const int* __restrict__ tgt,
                                                  float* __restrict__ rowloss, int rg0) {
  const int rl = blockIdx.x;
  const float* row = logits + (size_t)rl * VOCP;
  const int tid = threadIdx.x;
  float mx = -3.4e38f;
  for (int n = tid; n < VOC; n += 256) mx = fmaxf(mx, row[n]);
#pragma unroll
  for (int o = 1; o < 64; o <<= 1) mx = fmaxf(mx, __shfl_xor(mx, o));
  __shared__ float s1[4];
  if ((tid & 63) == 0) s1[tid >> 6] = mx;
  __syncthreads();
  mx = fmaxf(fmaxf(s1[0], s1[1]), fmaxf(s1[2], s1[3]));
  float sm = 0.f;
  for (int n = tid; n < VOC; n += 256) sm += __expf(row[n] - mx);
#pragma unroll
  for (int o = 1; o < 64; o <<= 1) sm += __shfl_xor(sm, o);
  __shared__ float s2[4];
  if ((tid & 63) == 0) s2[tid >> 6] = sm;
  __syncthreads();
  if (tid == 0) {
    float tot = s2[0] + s2[1] + s2[2] + s2[3];
    rowloss[rg0 + rl] = mx + __logf(tot) - row[tgt[rg0 + rl]];
  }
}

__global__ __launch_bounds__(256) void final_kernel(const float* __restrict__ rowloss,
                                                    float* __restrict__ out) {
  float s = 0.f;
  for (int n = threadIdx.x; n < 9984; n += 256) s += rowloss[n];
#pragma unroll
  for (int o = 1; o < 64; o <<= 1) s += __shfl_xor(s, o);
  __shared__ float sr[4];
  if ((threadIdx.x & 63) == 0) sr[threadIdx.x >> 6] = s;
  __syncthreads();
  if (threadIdx.x == 0) out[0] = (sr[0] + sr[1] + sr[2] + sr[3]) * (1.f / 256.f);
}

// ---------------------------------------------------------------------------------------
extern "C" void kernel_launch(void* const* d_in, const int* in_sizes, int n_in,
                              void* d_out, int out_size, void* d_ws, size_t ws_size,
                              hipStream_t stream) {
  const float* feat    = (const float*)d_in[0];
  const float* caption = (const float*)d_in[1];
  const float* coh     = (const float*)d_in[2];
  const float* W_ih1   = (const float*)d_in[3];
  const float* W_hh1   = (const float*)d_in[4];
  const float* b_ih1   = (const float*)d_in[5];
  const float* b_hh1   = (const float*)d_in[6];
  const float* W_ih2   = (const float*)d_in[7];
  const float* W_hh2   = (const float*)d_in[8];
  const float* b_ih2   = (const float*)d_in[9];
  const float* b_hh2   = (const float*)d_in[10];
  const float* W_out   = (const float*)d_in[11];
  const float* b_out   = (const float*)d_in[12];

  char* p = (char*)d_ws;
  auto take = [&](size_t bytes) { char* r = p; p += (bytes + 255) & ~(size_t)255; return r; };
  float* X1     = (float*)take(20480ull * 1024 * 4);   // feat @ W_ih1^T + b1sum, [b*80+t][g]
  float* Xc     = (float*)take(10240ull * 1024 * 4);   // caption @ W_ih2[:,:256]^T + b2sum
  float* H2dec  = (float*)take(9984ull * 256 * 4);
  float* logits = (float*)take((size_t)CHUNK_M * VOCP * 4);
  u16* Wih1b  = (u16*)take(1024ull * 4096 * 2);
  u16* Whh1b  = (u16*)take(1024ull * 256 * 2);
  u16* Wih2ab = (u16*)take(1024ull * 256 * 2);
  u16* Wcat2b = (u16*)take(1024ull * 512 * 2);
  u16* Woutb  = (u16*)take((size_t)VOCP * 256 * 2);
  u16* hcat   = (u16*)take(2ull * 256 * 512 * 2);      // hcat, c1, c2 contiguous (one memset)
  float* c1   = (float*)take(256ull * 256 * 4);
  float* c2   = (float*)take(256ull * 256 * 4);
  float* b1sum = (float*)take(1024 * 4);
  float* b2sum = (float*)take(1024 * 4);
  float* boutp = (float*)take(VOCP * 4);
  int*   tgt   = (int*)take(9984 * 4);
  float* rowloss = (float*)take(9984 * 4);

  // zero recurrent state (hcat|c1|c2 are contiguous)
  hipMemsetAsync(hcat, 0, 2ull * 256 * 512 * 2 + 2ull * 256 * 256 * 4, stream);
  bias_setup<<<dim3(24), dim3(256), 0, stream>>>(b_ih1, b_hh1, b_ih2, b_hh2, b_out,
                                                 b1sum, b2sum, boutp);
  auto pack = [&](u16* dst, int dld, int doff, const float* src, int sld, int soff,
                  int Wc, int R, int Rs) {
    int tot = Wc * R;
    pack_bf16<<<dim3((tot + 255) / 256), dim3(256), 0, stream>>>(dst, dld, doff, src, sld, soff,
                                                                 Wc, R, Rs);
  };
  pack(Wih1b, 4096, 0, W_ih1, 4096, 0, 4096, 1024, 1024);
  pack(Whh1b, 256, 0, W_hh1, 256, 0, 256, 1024, 1024);
  pack(Wih2ab, 256, 0, W_ih2, 512, 0, 256, 1024, 1024);     // W_ih2[:, :256]
  pack(Wcat2b, 512, 0, W_ih2, 512, 256, 256, 1024, 1024);   // W_ih2[:, 256:]
  pack(Wcat2b, 512, 256, W_hh2, 256, 0, 256, 1024, 1024);   // W_hh2
  pack(Woutb, 256, 0, W_out, 256, 0, 256, VOCP, VOC);       // zero-padded rows

  argmax_kernel<<<dim3(39 * 256), dim3(256), 0, stream>>>(coh, tgt);

  // big hoisted GEMMs (grid.x = N-tiles so A-tiles stay L2-hot across the 8 N-tiles)
  gemm_bf16<<<dim3(8, 160), dim3(256), 0, stream>>>(feat, Wih1b, b1sum, X1, 4096, 4096, 1024);
  gemm_bf16<<<dim3(8, 80), dim3(256), 0, stream>>>(caption, Wih2ab, b2sum, Xc, 256, 256, 1024);

  for (int t = 0; t <= 119; ++t)
    step_kernel<<<dim3(128), dim3(256), 0, stream>>>(t, X1, Xc, b1sum, b2sum,
                                                     Whh1b, Wcat2b, hcat, c1, c2, H2dec);

  for (int ch = 0; ch < 3; ++ch) {
    gemm_bf16<<<dim3(VOCP / 128, CHUNK_M / 128), dim3(256), 0, stream>>>(
        H2dec + (size_t)ch * CHUNK_M * 256, Woutb, boutp, logits, 256, 256, VOCP);
    nll_kernel<<<dim3(CHUNK_M), dim3(256), 0, stream>>>(logits, tgt, rowloss, ch * CHUNK_M);
  }
  final_kernel<<<dim3(1), dim3(256), 0, stream>>>(rowloss, (float*)d_out);
}